// Round 2
// baseline (429.400 us; speedup 1.0000x reference)
//
#include <hip/hip_runtime.h>
#include <stdint.h>

#define SEQ 2048
#define BATCH 2
#define HID 2048
#define NHEADS 16
#define HDIM 128
#define QKV_LD 6144
#define SCALE_F 0.08838834764831845f
#define LOG2E_F 1.4426950408889634f

typedef unsigned short u16;
using bf16x8 = __attribute__((ext_vector_type(8))) short;
using f32x4  = __attribute__((ext_vector_type(4))) float;

__device__ inline u16 f2bf(float f) {
  union { float f; uint32_t u; } c; c.f = f;
  uint32_t u = c.u;
  uint32_t r = (u + 0x7fffu + ((u >> 16) & 1u)) >> 16;
  return (u16)r;
}

__device__ inline void gl_lds16(const u16* g, u16* l) {
  __builtin_amdgcn_global_load_lds((const __attribute__((address_space(1))) void*)g,
                                   (__attribute__((address_space(3))) void*)l,
                                   16, 0, 0);
}

// One kernel converts all three inputs. Outputs contiguous in ws:
// [hs_bf | wqkv_bf (Q rows pre-scaled) | wout_bf].
__global__ void cvt_all(const float* __restrict__ hs, const float* __restrict__ wqkv,
                        const float* __restrict__ wout, u16* __restrict__ ws_out) {
  int i = blockIdx.x * blockDim.x + threadIdx.x;
  const float* src;
  int j;
  float sc = 1.0f;
  if (i < 2097152) { src = hs; j = i; }
  else if (i < 5242880) {
    j = i - 2097152; src = wqkv;
    const int f = j >> 9;
    if ((f % 384) < 128) sc = SCALE_F;             // Q rows carry the softmax scale
  } else { j = i - 5242880; src = wout; }
  float4 v = ((const float4*)src)[j];
  ushort4 o;
  o.x = f2bf(v.x * sc); o.y = f2bf(v.y * sc); o.z = f2bf(v.z * sc); o.w = f2bf(v.w * sc);
  ((ushort4*)ws_out)[i] = o;
}

// ============================================================================
// QKV GEMM: C[4096,6144] = A[4096,2048] @ B[6144,2048]^T, m201-style schedule.
// BM=BN=256, BK=64, 8 waves (2M x 4N), per-wave C = 128x64 (8x4 frags).
// LDS: double-buffered A/B tiles, 128 KiB total. Each K-tile = 4 phases
// {ds_read subtile || stage 2 gl_lds -> barrier -> setprio/16 MFMA -> [vmcnt(8)] -> barrier}.
// ks-half regions are contiguous (column-interleaved layout:
// slot = (row>>4)*64 + chunk*16 + (row&15)) so gl_lds' linear dest works and
// consecutive-8 lanes of ds_read_b128 hit 8 distinct 16B columns (0 conflicts).
// vmcnt counted (8 steady), never 0 until tail. Epilogue = MODE-1 (Q/K to qkv,
// V transposed to vt).
// ============================================================================
#define QK_M 4096
#define QK_N 6144
#define QK_K 2048
#define QK_T (QK_K / 64)   // 32

__global__ __launch_bounds__(512, 2)
void gemm256_qkv(const u16* __restrict__ A, const u16* __restrict__ Bw,
                 u16* __restrict__ Cout, u16* __restrict__ vt) {
  __shared__ __align__(16) u16 As[2][16384];   // [buf][ks*8192 + slot*8], 32 KB each
  __shared__ __align__(16) u16 Bs[2][16384];
  const int bm = blockIdx.x, bn = blockIdx.y;
  const int tid = threadIdx.x;
  const int wave = tid >> 6, lane = tid & 63;
  const int quad = lane >> 4, l16 = lane & 15;
  const int wm = (wave >> 2) * 128, wn = (wave & 3) * 64;
  f32x4 acc[8][4] = {};

  const u16* Ablk = A + (size_t)(bm * 256) * QK_K;
  const u16* Bblk = Bw + (size_t)(bn * 256) * QK_K;

  // stage one ks-half (256 rows x 32 cols = 16 KB) of A or B: 2 gl_lds/thread.
  auto stageA = [&](int t, int ks, int buf) {
    #pragma unroll
    for (int p = 0; p < 2; ++p) {
      int j = p * 512 + tid;                       // slot index
      int row = ((j >> 6) << 4) + (j & 15);
      int c = (j >> 4) & 3;
      gl_lds16(Ablk + (size_t)row * QK_K + t * 64 + ks * 32 + c * 8,
               &As[buf][ks * 8192 + (p * 512 + wave * 64) * 8]);
    }
  };
  auto stageB = [&](int t, int ks, int buf) {
    #pragma unroll
    for (int p = 0; p < 2; ++p) {
      int j = p * 512 + tid;
      int row = ((j >> 6) << 4) + (j & 15);
      int c = (j >> 4) & 3;
      gl_lds16(Bblk + (size_t)row * QK_K + t * 64 + ks * 32 + c * 8,
               &Bs[buf][ks * 8192 + (p * 512 + wave * 64) * 8]);
    }
  };

  // prologue: tile0 (both ks halves) + tile1 ks0 = 12 loads; retire tile0-ks0.
  stageA(0, 0, 0); stageB(0, 0, 0);
  stageA(0, 1, 0); stageB(0, 1, 0);
  stageA(1, 0, 1); stageB(1, 0, 1);
  asm volatile("s_waitcnt vmcnt(8)" ::: "memory");
  __builtin_amdgcn_s_barrier();
  __builtin_amdgcn_sched_barrier(0);

  for (int t = 0; t < QK_T; ++t) {
    const int cb = t & 1;
    const u16* Ab = &As[cb][0];
    const u16* Bb = &Bs[cb][0];
    bf16x8 af[4], bfr[4];

    // ---- phase 0: ks0, m-half 0 (reads bfr too) ----
    #pragma unroll
    for (int mt = 0; mt < 4; ++mt) {
      int row = wm + mt * 16 + l16;
      af[mt] = *(const bf16x8*)&Ab[(((row >> 4) << 6) + quad * 16 + (row & 15)) * 8];
    }
    #pragma unroll
    for (int nt = 0; nt < 4; ++nt) {
      int row = wn + nt * 16 + l16;
      bfr[nt] = *(const bf16x8*)&Bb[(((row >> 4) << 6) + quad * 16 + (row & 15)) * 8];
    }
    if (t + 1 < QK_T) stageA(t + 1, 1, cb ^ 1);
    __builtin_amdgcn_s_barrier();
    __builtin_amdgcn_s_setprio(1);
    #pragma unroll
    for (int mt = 0; mt < 4; ++mt)
      #pragma unroll
      for (int nt = 0; nt < 4; ++nt)
        acc[mt][nt] = __builtin_amdgcn_mfma_f32_16x16x32_bf16(af[mt], bfr[nt], acc[mt][nt], 0, 0, 0);
    __builtin_amdgcn_s_setprio(0);
    __builtin_amdgcn_s_barrier();

    // ---- phase 1: ks0, m-half 1 ----
    #pragma unroll
    for (int mt = 0; mt < 4; ++mt) {
      int row = wm + 64 + mt * 16 + l16;
      af[mt] = *(const bf16x8*)&Ab[(((row >> 4) << 6) + quad * 16 + (row & 15)) * 8];
    }
    if (t + 1 < QK_T) stageB(t + 1, 1, cb ^ 1);
    __builtin_amdgcn_s_barrier();
    __builtin_amdgcn_s_setprio(1);
    #pragma unroll
    for (int mt = 0; mt < 4; ++mt)
      #pragma unroll
      for (int nt = 0; nt < 4; ++nt)
        acc[4 + mt][nt] = __builtin_amdgcn_mfma_f32_16x16x32_bf16(af[mt], bfr[nt], acc[4 + mt][nt], 0, 0, 0);
    __builtin_amdgcn_s_setprio(0);
    if (t < QK_T - 1) asm volatile("s_waitcnt vmcnt(8)" ::: "memory");
    else              asm volatile("s_waitcnt vmcnt(0)" ::: "memory");
    __builtin_amdgcn_s_barrier();
    __builtin_amdgcn_sched_barrier(0);

    // ---- phase 2: ks1, m-half 0 (reads bfr @ks1) ----
    #pragma unroll
    for (int mt = 0; mt < 4; ++mt) {
      int row = wm + mt * 16 + l16;
      af[mt] = *(const bf16x8*)&Ab[8192 + (((row >> 4) << 6) + quad * 16 + (row & 15)) * 8];
    }
    #pragma unroll
    for (int nt = 0; nt < 4; ++nt) {
      int row = wn + nt * 16 + l16;
      bfr[nt] = *(const bf16x8*)&Bb[8192 + (((row >> 4) << 6) + quad * 16 + (row & 15)) * 8];
    }
    if (t + 2 < QK_T) stageA(t + 2, 0, cb);
    __builtin_amdgcn_s_barrier();
    __builtin_amdgcn_s_setprio(1);
    #pragma unroll
    for (int mt = 0; mt < 4; ++mt)
      #pragma unroll
      for (int nt = 0; nt < 4; ++nt)
        acc[mt][nt] = __builtin_amdgcn_mfma_f32_16x16x32_bf16(af[mt], bfr[nt], acc[mt][nt], 0, 0, 0);
    __builtin_amdgcn_s_setprio(0);
    __builtin_amdgcn_s_barrier();

    // ---- phase 3: ks1, m-half 1 ----
    #pragma unroll
    for (int mt = 0; mt < 4; ++mt) {
      int row = wm + 64 + mt * 16 + l16;
      af[mt] = *(const bf16x8*)&Ab[8192 + (((row >> 4) << 6) + quad * 16 + (row & 15)) * 8];
    }
    if (t + 2 < QK_T) stageB(t + 2, 0, cb);
    __builtin_amdgcn_s_barrier();
    __builtin_amdgcn_s_setprio(1);
    #pragma unroll
    for (int mt = 0; mt < 4; ++mt)
      #pragma unroll
      for (int nt = 0; nt < 4; ++nt)
        acc[4 + mt][nt] = __builtin_amdgcn_mfma_f32_16x16x32_bf16(af[mt], bfr[nt], acc[4 + mt][nt], 0, 0, 0);
    __builtin_amdgcn_s_setprio(0);
    if (t < QK_T - 2)       asm volatile("s_waitcnt vmcnt(8)" ::: "memory");
    else if (t == QK_T - 2) asm volatile("s_waitcnt vmcnt(4)" ::: "memory");
    else                    asm volatile("s_waitcnt vmcnt(0)" ::: "memory");
    __builtin_amdgcn_s_barrier();
    __builtin_amdgcn_sched_barrier(0);
  }

  // Epilogue (MODE 1): per 16-col fragment, role = Q/K (to qkv) or V (transposed to vt).
  #pragma unroll
  for (int ntf = 0; ntf < 4; ++ntf) {
    const int coff = wn + ntf * 16;                // 0..240, multiple of 16
    const int g = bn * 2 + (coff >> 7);
    const int h = g / 3;
    if ((g % 3) == 2) {
      const int hd = (coff & 127) + l16;
      u16* vt0 = vt + ((size_t)h * HDIM) * SEQ;                  // b=0
      u16* vt1 = vt + ((size_t)(NHEADS + h) * HDIM) * SEQ;       // b=1
      #pragma unroll
      for (int mt = 0; mt < 8; ++mt) {
        const int s0 = (bm * 256 + wm + mt * 16 + quad * 4) >> 1;
        uint32_t w0 = (uint32_t)f2bf(acc[mt][ntf][0]) | ((uint32_t)f2bf(acc[mt][ntf][2]) << 16);
        uint32_t w1 = (uint32_t)f2bf(acc[mt][ntf][1]) | ((uint32_t)f2bf(acc[mt][ntf][3]) << 16);
        *(uint32_t*)&vt0[(size_t)hd * SEQ + s0] = w0;
        *(uint32_t*)&vt1[(size_t)hd * SEQ + s0] = w1;
      }
    } else {
      const int col = bn * 256 + coff + l16;
      #pragma unroll
      for (int mt = 0; mt < 8; ++mt)
        #pragma unroll
        for (int r = 0; r < 4; ++r) {
          const int row = bm * 256 + wm + mt * 16 + quad * 4 + r;
          Cout[(size_t)row * QK_N + col] = f2bf(acc[mt][ntf][r]);
        }
    }
  }
}

// ============================================================================
// R0's proven 128x128 GEMM (845 TF-class): used for the out-projection only.
// C[M,N] = A[M,K] @ B[N,K]^T, bf16 in, fp32 out. XOR chunk swizzle, gl_lds x16.
// ============================================================================
template<int MODE>
__global__ __launch_bounds__(256)
void gemm_bt(const u16* __restrict__ A, const u16* __restrict__ Bw,
             void* __restrict__ Cout, u16* __restrict__ vt, int M, int N, int K) {
  __shared__ __align__(16) u16 Asx[128 * 64];
  __shared__ __align__(16) u16 Bsx[128 * 64];
  const int bm = blockIdx.x, bn = blockIdx.y;
  const int tid = threadIdx.x;
  const int wave = tid >> 6, lane = tid & 63;
  const int quad = lane >> 4, l16 = lane & 15;
  const int wm = (wave >> 1) * 64, wn = (wave & 1) * 64;
  f32x4 acc[4][4] = {};

  const u16* Ablk = A + (size_t)(bm * 128) * K;
  const u16* Bblk = Bw + (size_t)(bn * 128) * K;

  for (int k0 = 0; k0 < K; k0 += 64) {
    __syncthreads();
    #pragma unroll
    for (int p = 0; p < 4; ++p) {
      int j = p * 256 + tid;
      int r = j >> 3, cs = j & 7, c = cs ^ (r & 7);
      gl_lds16(Ablk + (size_t)r * K + k0 + c * 8, Asx + (p * 256 + wave * 64) * 8);
      gl_lds16(Bblk + (size_t)r * K + k0 + c * 8, Bsx + (p * 256 + wave * 64) * 8);
    }
    __syncthreads();
    #pragma unroll
    for (int ks = 0; ks < 2; ++ks) {
      bf16x8 af[4], bfr[4];
      #pragma unroll
      for (int mt = 0; mt < 4; ++mt) {
        int row = wm + mt * 16 + l16;
        int cc = (ks * 4 + quad) ^ (row & 7);
        af[mt] = *(const bf16x8*)&Asx[(row * 8 + cc) * 8];
      }
      #pragma unroll
      for (int nt = 0; nt < 4; ++nt) {
        int row = wn + nt * 16 + l16;
        int cc = (ks * 4 + quad) ^ (row & 7);
        bfr[nt] = *(const bf16x8*)&Bsx[(row * 8 + cc) * 8];
      }
      #pragma unroll
      for (int mt = 0; mt < 4; ++mt)
        #pragma unroll
        for (int nt = 0; nt < 4; ++nt)
          acc[mt][nt] = __builtin_amdgcn_mfma_f32_16x16x32_bf16(af[mt], bfr[nt], acc[mt][nt], 0, 0, 0);
    }
  }

  #pragma unroll
  for (int mt = 0; mt < 4; ++mt)
    #pragma unroll
    for (int nt = 0; nt < 4; ++nt)
      #pragma unroll
      for (int r = 0; r < 4; ++r) {
        int row = bm * 128 + wm + mt * 16 + quad * 4 + r;
        int col = bn * 128 + wn + nt * 16 + l16;
        float v = acc[mt][nt][r];
        if (MODE == 1) ((u16*)Cout)[(size_t)row * N + col] = f2bf(v);
        else           ((float*)Cout)[(size_t)row * N + col] = v;
      }
}

// Flash attention, no-max softmax (Q pre-scaled; scores bounded so exp can't overflow).
// Transposed formulation: S^T = K Q^T; P^T to LDS (XOR-swizzled b64 writes);
// O^T = V P via A=Vt rows (incl. ones-row for l); packed 8B ctx stores.
__global__ __launch_bounds__(512, 2)
void attn(const u16* __restrict__ qkv, const u16* __restrict__ vt_g, u16* __restrict__ ctx) {
  const int qt = blockIdx.x, head = blockIdx.y, b = blockIdx.z;
  const int q0 = qt * 256;
  __shared__ __align__(16) u16 Ks[64 * 128];    // 16 KB: 64 key-rows x 16 chunks
  __shared__ __align__(16) u16 Vt[144 * 64];    // 18 KB: 128 hd-rows + 16 ones/zero rows
  __shared__ __align__(16) u16 PsT[256 * 64];   // 32 KB: [q][key], swizzled chunks
  const int tid = threadIdx.x;
  const int wave = tid >> 6, lane = tid & 63;
  const int quad = lane >> 4, l16 = lane & 15;

  const u16* qkv_bh = qkv + (size_t)b * QKV_LD + head * 384;
  const u16* vt = vt_g + (size_t)(b * NHEADS + head) * HDIM * SEQ;

  // ones/zero rows 128..143 of Vt (row 128 = 1.0 bf16, rest 0); written once.
  if (tid < 128) {
    const int row = 128 + (tid >> 3), c = tid & 7;
    const u16 v = (row == 128) ? (u16)0x3F80 : (u16)0;
    ushort4 q4; q4.x = v; q4.y = v; q4.z = v; q4.w = v;
    *(ushort4*)&Vt[(row * 8 + c) * 8] = q4;
    *(ushort4*)&Vt[(row * 8 + c) * 8 + 4] = q4;
  }

  // ---- stage Q through Ks buffer (4 rounds of 64 rows), frags into registers ----
  bf16x8 qf[2][4];   // [q-tile nt][ks]; used as B-operand later (same reg layout as A)
  #pragma unroll
  for (int h = 0; h < 4; ++h) {
    __syncthreads();
    #pragma unroll
    for (int p = 0; p < 2; ++p) {
      int j = p * 512 + tid;
      int r = j >> 4, cs = j & 15, c = cs ^ (r & 7);
      gl_lds16(qkv_bh + (size_t)(q0 + h * 64 + r) * (BATCH * QKV_LD) + c * 8,
               Ks + (p * 512 + wave * 64) * 8);
    }
    __syncthreads();
    if ((wave >> 1) == h) {
      #pragma unroll
      for (int nt = 0; nt < 2; ++nt)
        #pragma unroll
        for (int ks = 0; ks < 4; ++ks) {
          int row = (wave & 1) * 32 + nt * 16 + l16;
          int cc = (ks * 4 + quad) ^ (row & 7);
          qf[nt][ks] = *(const bf16x8*)&Ks[(row * 16 + cc) * 8];
        }
    }
  }

  f32x4 ot[9][2] = {};   // [hd-tile mt (8=ones/l)][q-tile nt]

  for (int kt = 0; kt < SEQ; kt += 64) {
    __syncthreads();
    // stage K tile (64 rows x 16 chunks)
    #pragma unroll
    for (int p = 0; p < 2; ++p) {
      int j = p * 512 + tid;
      int r = j >> 4, cs = j & 15, c = cs ^ (r & 7);
      gl_lds16(qkv_bh + (size_t)(kt + r) * (BATCH * QKV_LD) + 128 + c * 8,
               Ks + (p * 512 + wave * 64) * 8);
    }
    // stage Vt tile (128 rows x 8 chunks)
    #pragma unroll
    for (int p = 0; p < 2; ++p) {
      int j = p * 512 + tid;
      int hd = j >> 3, cs = j & 7, c = cs ^ (hd & 7);
      gl_lds16(vt + (size_t)hd * SEQ + kt + c * 8,
               Vt + (p * 512 + wave * 64) * 8);
    }
    __syncthreads();

    // S^T = K Q^T  (wave: 64 keys x 32 q-rows); element (key=mt*16+quad*4+r, q=nt*16+l16)
    f32x4 st[4][2] = {};
    #pragma unroll
    for (int ks = 0; ks < 4; ++ks) {
      bf16x8 kf[4];
      #pragma unroll
      for (int mt = 0; mt < 4; ++mt) {
        int key = mt * 16 + l16;
        int cc = (ks * 4 + quad) ^ (key & 7);
        kf[mt] = *(const bf16x8*)&Ks[(key * 16 + cc) * 8];
      }
      #pragma unroll
      for (int mt = 0; mt < 4; ++mt)
        #pragma unroll
        for (int nt = 0; nt < 2; ++nt)
          st[mt][nt] = __builtin_amdgcn_mfma_f32_16x16x32_bf16(kf[mt], qf[nt][ks], st[mt][nt], 0, 0, 0);
    }

    // p = exp2(s*log2e) -> bf16; 4 consecutive keys per lane -> one b64 write each
    #pragma unroll
    for (int mt = 0; mt < 4; ++mt)
      #pragma unroll
      for (int nt = 0; nt < 2; ++nt) {
        ushort4 pk;
        union { float f; uint32_t u; } cv;
        cv.f = __builtin_amdgcn_exp2f(st[mt][nt][0] * LOG2E_F); pk.x = (u16)(cv.u >> 16);
        cv.f = __builtin_amdgcn_exp2f(st[mt][nt][1] * LOG2E_F); pk.y = (u16)(cv.u >> 16);
        cv.f = __builtin_amdgcn_exp2f(st[mt][nt][2] * LOG2E_F); pk.z = (u16)(cv.u >> 16);
        cv.f = __builtin_amdgcn_exp2f(st[mt][nt][3] * LOG2E_F); pk.w = (u16)(cv.u >> 16);
        const int q = wave * 32 + nt * 16 + l16;
        const int kc = mt * 2 + (quad >> 1);
        *(ushort4*)&PsT[q * 64 + ((kc ^ (l16 & 7)) * 8 + (quad & 1) * 4)] = pk;
      }

    // O^T += V P  (A=Vt rows incl. ones, B=P^T; PsT rows are wave-private)
    #pragma unroll
    for (int ks = 0; ks < 2; ++ks) {
      bf16x8 pf[2], vf[9];
      #pragma unroll
      for (int nt = 0; nt < 2; ++nt) {
        const int q = wave * 32 + nt * 16 + l16;
        const int cc = (ks * 4 + quad) ^ (l16 & 7);
        pf[nt] = *(const bf16x8*)&PsT[q * 64 + cc * 8];
      }
      #pragma unroll
      for (int mt = 0; mt < 9; ++mt) {
        const int hd = mt * 16 + l16;
        const int cc = (ks * 4 + quad) ^ (hd & 7);
        vf[mt] = *(const bf16x8*)&Vt[(hd * 8 + cc) * 8];
      }
      #pragma unroll
      for (int mt = 0; mt < 9; ++mt)
        #pragma unroll
        for (int nt = 0; nt < 2; ++nt)
          ot[mt][nt] = __builtin_amdgcn_mfma_f32_16x16x32_bf16(vf[mt], pf[nt], ot[mt][nt], 0, 0, 0);
    }
  }

  // epilogue: l[q] lives in ot[8][nt][0] at quad-0 lanes (m=0 row of ones-tile)
  #pragma unroll
  for (int nt = 0; nt < 2; ++nt) {
    const float lv = __shfl(ot[8][nt][0], l16);
    const float inv_l = 1.0f / lv;
    const int s = q0 + wave * 32 + nt * 16 + l16;
    u16* dst = ctx + ((size_t)s * BATCH + b) * HID + head * HDIM;
    #pragma unroll
    for (int mt = 0; mt < 8; ++mt) {
      ushort4 w;
      w.x = f2bf(ot[mt][nt][0] * inv_l);
      w.y = f2bf(ot[mt][nt][1] * inv_l);
      w.z = f2bf(ot[mt][nt][2] * inv_l);
      w.w = f2bf(ot[mt][nt][3] * inv_l);
      *(ushort4*)&dst[mt * 16 + quad * 4] = w;
    }
  }
}

extern "C" void kernel_launch(void* const* d_in, const int* in_sizes, int n_in,
                              void* d_out, int out_size, void* d_ws, size_t ws_size,
                              hipStream_t stream) {
  const float* hs   = (const float*)d_in[0];
  const float* wqkv = (const float*)d_in[1];
  const float* wout = (const float*)d_in[2];
  float* out = (float*)d_out;
  char* ws = (char*)d_ws;

  u16* hs_bf   = (u16*)(ws);               // 16 MB; dead after QKV GEMM
  u16* wqkv_bf = (u16*)(ws + 16777216);    // 24 MB
  u16* wout_bf = (u16*)(ws + 41943040);    //  8 MB
  u16* qkv_bf  = (u16*)(ws + 50331648);    // 48 MB (V-part unused/unwritten)
  u16* vt_bf   = (u16*)(ws + 100663296);   // 16 MB, written by QKV GEMM epilogue
  u16* ctx_bf  = hs_bf;                    // reuse: attn runs after QKV GEMM

  cvt_all<<<24576, 256, 0, stream>>>(hs, wqkv, wout, (u16*)ws);

  gemm256_qkv<<<dim3(16, 24), 512, 0, stream>>>(hs_bf, wqkv_bf, qkv_bf, vt_bf);

  attn<<<dim3(8, NHEADS, BATCH), 512, 0, stream>>>(qkv_bf, vt_bf, ctx_bf);

  gemm_bt<0><<<dim3(32, 16), 256, 0, stream>>>(ctx_bf, wout_bf, out, nullptr, 4096, 2048, 2048);
}

// Round 3
// 393.549 us; speedup vs baseline: 1.0911x; 1.0911x over previous
//
#include <hip/hip_runtime.h>
#include <stdint.h>

#define SEQ 2048
#define BATCH 2
#define HID 2048
#define NHEADS 16
#define HDIM 128
#define QKV_LD 6144
#define SCALE_F 0.08838834764831845f
#define LOG2E_F 1.4426950408889634f

typedef unsigned short u16;
using bf16x8 = __attribute__((ext_vector_type(8))) short;
using f32x4  = __attribute__((ext_vector_type(4))) float;

__device__ inline u16 f2bf(float f) {
  union { float f; uint32_t u; } c; c.f = f;
  uint32_t u = c.u;
  uint32_t r = (u + 0x7fffu + ((u >> 16) & 1u)) >> 16;
  return (u16)r;
}

__device__ inline void gl_lds16(const u16* g, u16* l) {
  __builtin_amdgcn_global_load_lds((const __attribute__((address_space(1))) void*)g,
                                   (__attribute__((address_space(3))) void*)l,
                                   16, 0, 0);
}

// One kernel converts all three inputs. Outputs contiguous in ws:
// [hs_bf | wqkv_bf (Q rows pre-scaled) | wout_bf].
__global__ void cvt_all(const float* __restrict__ hs, const float* __restrict__ wqkv,
                        const float* __restrict__ wout, u16* __restrict__ ws_out) {
  int i = blockIdx.x * blockDim.x + threadIdx.x;
  const float* src;
  int j;
  float sc = 1.0f;
  if (i < 2097152) { src = hs; j = i; }
  else if (i < 5242880) {
    j = i - 2097152; src = wqkv;
    const int f = j >> 9;
    if ((f % 384) < 128) sc = SCALE_F;             // Q rows carry the softmax scale
  } else { j = i - 5242880; src = wout; }
  float4 v = ((const float4*)src)[j];
  ushort4 o;
  o.x = f2bf(v.x * sc); o.y = f2bf(v.y * sc); o.z = f2bf(v.z * sc); o.w = f2bf(v.w * sc);
  ((ushort4*)ws_out)[i] = o;
}

// C[M,N] = A[M,K] @ B[N,K]^T, bf16 in, fp32 acc. 128x128 tile, BK=64, gl_lds x16
// staging with XOR chunk swizzle (0 bank conflicts, R5-measured).
// MODE 1 (QKV): bf16 out; V-blocks (bn%3==2, head=bn/3) written TRANSPOSED to vt
//   as packed 4B stores (two seq-positions per store), qkv V-part not written.
// MODE 0: f32 out, no vt.
template<int MODE>
__global__ __launch_bounds__(256)
void gemm_bt(const u16* __restrict__ A, const u16* __restrict__ Bw,
             void* __restrict__ Cout, u16* __restrict__ vt, int M, int N, int K) {
  __shared__ __align__(16) u16 As[128 * 64];
  __shared__ __align__(16) u16 Bs[128 * 64];
  const int bm = blockIdx.x, bn = blockIdx.y;
  const int tid = threadIdx.x;
  const int wave = tid >> 6, lane = tid & 63;
  const int quad = lane >> 4, l16 = lane & 15;
  const int wm = (wave >> 1) * 64, wn = (wave & 1) * 64;
  f32x4 acc[4][4] = {};

  const u16* Ablk = A + (size_t)(bm * 128) * K;
  const u16* Bblk = Bw + (size_t)(bn * 128) * K;

  for (int k0 = 0; k0 < K; k0 += 64) {
    __syncthreads();
    #pragma unroll
    for (int p = 0; p < 4; ++p) {
      int j = p * 256 + tid;
      int r = j >> 3, cs = j & 7, c = cs ^ (r & 7);
      gl_lds16(Ablk + (size_t)r * K + k0 + c * 8, As + (p * 256 + wave * 64) * 8);
      gl_lds16(Bblk + (size_t)r * K + k0 + c * 8, Bs + (p * 256 + wave * 64) * 8);
    }
    __syncthreads();
    #pragma unroll
    for (int ks = 0; ks < 2; ++ks) {
      bf16x8 af[4], bfr[4];
      #pragma unroll
      for (int mt = 0; mt < 4; ++mt) {
        int row = wm + mt * 16 + l16;
        int cc = (ks * 4 + quad) ^ (row & 7);
        af[mt] = *(const bf16x8*)&As[(row * 8 + cc) * 8];
      }
      #pragma unroll
      for (int nt = 0; nt < 4; ++nt) {
        int row = wn + nt * 16 + l16;
        int cc = (ks * 4 + quad) ^ (row & 7);
        bfr[nt] = *(const bf16x8*)&Bs[(row * 8 + cc) * 8];
      }
      #pragma unroll
      for (int mt = 0; mt < 4; ++mt)
        #pragma unroll
        for (int nt = 0; nt < 4; ++nt)
          acc[mt][nt] = __builtin_amdgcn_mfma_f32_16x16x32_bf16(af[mt], bfr[nt], acc[mt][nt], 0, 0, 0);
    }
  }

  if (MODE == 1 && (bn % 3) == 2) {
    // V block: C rows are tokens (row = s*2+b), cols are head-dims hd of head bn/3.
    // r=0:(s0,b0) r=1:(s0,b1) r=2:(s0+1,b0) r=3:(s0+1,b1); pack (r0,r2)/(r1,r3) -> 4B.
    const int h = bn / 3;
    u16* vt0 = vt + ((size_t)h * HDIM) * SEQ;                     // b=0
    u16* vt1 = vt + ((size_t)(NHEADS + h) * HDIM) * SEQ;          // b=1
    #pragma unroll
    for (int mt = 0; mt < 4; ++mt)
      #pragma unroll
      for (int nt = 0; nt < 4; ++nt) {
        const int hd = wn + nt * 16 + l16;
        const int s0 = (bm * 128 + wm + mt * 16 + quad * 4) >> 1;
        uint32_t w0 = (uint32_t)f2bf(acc[mt][nt][0]) | ((uint32_t)f2bf(acc[mt][nt][2]) << 16);
        uint32_t w1 = (uint32_t)f2bf(acc[mt][nt][1]) | ((uint32_t)f2bf(acc[mt][nt][3]) << 16);
        *(uint32_t*)&vt0[(size_t)hd * SEQ + s0] = w0;
        *(uint32_t*)&vt1[(size_t)hd * SEQ + s0] = w1;
      }
    return;
  }

  #pragma unroll
  for (int mt = 0; mt < 4; ++mt)
    #pragma unroll
    for (int nt = 0; nt < 4; ++nt)
      #pragma unroll
      for (int r = 0; r < 4; ++r) {
        int row = bm * 128 + wm + mt * 16 + quad * 4 + r;
        int col = bn * 128 + wn + nt * 16 + l16;
        float v = acc[mt][nt][r];
        if (MODE == 1) ((u16*)Cout)[(size_t)row * N + col] = f2bf(v);
        else           ((float*)Cout)[(size_t)row * N + col] = v;
      }
}

// Flash attention, no-max softmax (Q pre-scaled; scores bounded so exp can't overflow).
// R3: QBLK=128 (was 256) -> grid 512 blocks = 2 blocks/CU. LDS 50 KB, VGPR capped
// at 128 via __launch_bounds__(512,4) so both blocks are resident; the second
// block's compute hides the first's __syncthreads staging drain (m114 mechanism).
// Per wave: 16 q-rows. Same math/layout as R0, only work partitioning changed.
__global__ __launch_bounds__(512, 4)
void attn(const u16* __restrict__ qkv, const u16* __restrict__ vt_g, u16* __restrict__ ctx) {
  const int qt = blockIdx.x, head = blockIdx.y, b = blockIdx.z;
  const int q0 = qt * 128;
  __shared__ __align__(16) u16 Ks[64 * 128];    // 16 KB: 64 key-rows x 16 chunks
  __shared__ __align__(16) u16 Vt[144 * 64];    // 18 KB: 128 hd-rows + 16 ones/zero rows
  __shared__ __align__(16) u16 PsT[128 * 64];   // 16 KB: [q][key], swizzled chunks
  const int tid = threadIdx.x;
  const int wave = tid >> 6, lane = tid & 63;
  const int quad = lane >> 4, l16 = lane & 15;

  const u16* qkv_bh = qkv + (size_t)b * QKV_LD + head * 384;
  const u16* vt = vt_g + (size_t)(b * NHEADS + head) * HDIM * SEQ;

  // ones/zero rows 128..143 of Vt (row 128 = 1.0 bf16, rest 0); written once.
  if (tid < 128) {
    const int row = 128 + (tid >> 3), c = tid & 7;
    const u16 v = (row == 128) ? (u16)0x3F80 : (u16)0;
    ushort4 q4; q4.x = v; q4.y = v; q4.z = v; q4.w = v;
    *(ushort4*)&Vt[(row * 8 + c) * 8] = q4;
    *(ushort4*)&Vt[(row * 8 + c) * 8 + 4] = q4;
  }

  // ---- stage Q through Ks buffer (2 rounds of 64 rows), frags into registers ----
  // wave w owns q-rows [w*16, w*16+16): round h = w>>2, buffer row (w&3)*16 + l16.
  bf16x8 qf[4];   // [ks]; used as B-operand later (same reg layout as A)
  #pragma unroll
  for (int h = 0; h < 2; ++h) {
    __syncthreads();
    #pragma unroll
    for (int p = 0; p < 2; ++p) {
      int j = p * 512 + tid;
      int r = j >> 4, cs = j & 15, c = cs ^ (r & 7);
      gl_lds16(qkv_bh + (size_t)(q0 + h * 64 + r) * (BATCH * QKV_LD) + c * 8,
               Ks + (p * 512 + wave * 64) * 8);
    }
    __syncthreads();
    if ((wave >> 2) == h) {
      #pragma unroll
      for (int ks = 0; ks < 4; ++ks) {
        int row = (wave & 3) * 16 + l16;
        int cc = (ks * 4 + quad) ^ (row & 7);
        qf[ks] = *(const bf16x8*)&Ks[(row * 16 + cc) * 8];
      }
    }
  }

  f32x4 ot[9] = {};   // [hd-tile mt (8=ones/l)]

  for (int kt = 0; kt < SEQ; kt += 64) {
    __syncthreads();
    // stage K tile (64 rows x 16 chunks)
    #pragma unroll
    for (int p = 0; p < 2; ++p) {
      int j = p * 512 + tid;
      int r = j >> 4, cs = j & 15, c = cs ^ (r & 7);
      gl_lds16(qkv_bh + (size_t)(kt + r) * (BATCH * QKV_LD) + 128 + c * 8,
               Ks + (p * 512 + wave * 64) * 8);
    }
    // stage Vt tile (128 rows x 8 chunks)
    #pragma unroll
    for (int p = 0; p < 2; ++p) {
      int j = p * 512 + tid;
      int hd = j >> 3, cs = j & 7, c = cs ^ (hd & 7);
      gl_lds16(vt + (size_t)hd * SEQ + kt + c * 8,
               Vt + (p * 512 + wave * 64) * 8);
    }
    __syncthreads();

    // S^T = K Q^T  (wave: 64 keys x 16 q-rows); element (key=mt*16+quad*4+r, q=l16)
    f32x4 st[4] = {};
    #pragma unroll
    for (int ks = 0; ks < 4; ++ks) {
      bf16x8 kf[4];
      #pragma unroll
      for (int mt = 0; mt < 4; ++mt) {
        int key = mt * 16 + l16;
        int cc = (ks * 4 + quad) ^ (key & 7);
        kf[mt] = *(const bf16x8*)&Ks[(key * 16 + cc) * 8];
      }
      #pragma unroll
      for (int mt = 0; mt < 4; ++mt)
        st[mt] = __builtin_amdgcn_mfma_f32_16x16x32_bf16(kf[mt], qf[ks], st[mt], 0, 0, 0);
    }

    // p = exp2(s*log2e) -> bf16; 4 consecutive keys per lane -> one b64 write each
    #pragma unroll
    for (int mt = 0; mt < 4; ++mt) {
      ushort4 pk;
      union { float f; uint32_t u; } cv;
      cv.f = __builtin_amdgcn_exp2f(st[mt][0] * LOG2E_F); pk.x = (u16)(cv.u >> 16);
      cv.f = __builtin_amdgcn_exp2f(st[mt][1] * LOG2E_F); pk.y = (u16)(cv.u >> 16);
      cv.f = __builtin_amdgcn_exp2f(st[mt][2] * LOG2E_F); pk.z = (u16)(cv.u >> 16);
      cv.f = __builtin_amdgcn_exp2f(st[mt][3] * LOG2E_F); pk.w = (u16)(cv.u >> 16);
      const int q = wave * 16 + l16;
      const int kc = mt * 2 + (quad >> 1);
      *(ushort4*)&PsT[q * 64 + ((kc ^ (l16 & 7)) * 8 + (quad & 1) * 4)] = pk;
    }

    // O^T += V P  (A=Vt rows incl. ones, B=P^T; PsT rows are wave-private)
    #pragma unroll
    for (int ks = 0; ks < 2; ++ks) {
      bf16x8 pf, vf[9];
      {
        const int q = wave * 16 + l16;
        const int cc = (ks * 4 + quad) ^ (l16 & 7);
        pf = *(const bf16x8*)&PsT[q * 64 + cc * 8];
      }
      #pragma unroll
      for (int mt = 0; mt < 9; ++mt) {
        const int hd = mt * 16 + l16;
        const int cc = (ks * 4 + quad) ^ (hd & 7);
        vf[mt] = *(const bf16x8*)&Vt[(hd * 8 + cc) * 8];
      }
      #pragma unroll
      for (int mt = 0; mt < 9; ++mt)
        ot[mt] = __builtin_amdgcn_mfma_f32_16x16x32_bf16(vf[mt], pf, ot[mt], 0, 0, 0);
    }
  }

  // epilogue: l[q] lives in ot[8][0] at quad-0 lanes (m=0 row of ones-tile)
  {
    const float lv = __shfl(ot[8][0], l16);
    const float inv_l = 1.0f / lv;
    const int s = q0 + wave * 16 + l16;
    u16* dst = ctx + ((size_t)s * BATCH + b) * HID + head * HDIM;
    #pragma unroll
    for (int mt = 0; mt < 8; ++mt) {
      ushort4 w;
      w.x = f2bf(ot[mt][0] * inv_l);
      w.y = f2bf(ot[mt][1] * inv_l);
      w.z = f2bf(ot[mt][2] * inv_l);
      w.w = f2bf(ot[mt][3] * inv_l);
      *(ushort4*)&dst[mt * 16 + quad * 4] = w;
    }
  }
}

extern "C" void kernel_launch(void* const* d_in, const int* in_sizes, int n_in,
                              void* d_out, int out_size, void* d_ws, size_t ws_size,
                              hipStream_t stream) {
  const float* hs   = (const float*)d_in[0];
  const float* wqkv = (const float*)d_in[1];
  const float* wout = (const float*)d_in[2];
  float* out = (float*)d_out;
  char* ws = (char*)d_ws;

  u16* hs_bf   = (u16*)(ws);               // 16 MB; dead after QKV GEMM
  u16* wqkv_bf = (u16*)(ws + 16777216);    // 24 MB
  u16* wout_bf = (u16*)(ws + 41943040);    //  8 MB
  u16* qkv_bf  = (u16*)(ws + 50331648);    // 48 MB (V-part unused/unwritten)
  u16* vt_bf   = (u16*)(ws + 100663296);   // 16 MB, written by QKV GEMM epilogue
  u16* ctx_bf  = hs_bf;                    // reuse: attn runs after QKV GEMM

  cvt_all<<<24576, 256, 0, stream>>>(hs, wqkv, wout, (u16*)ws);

  gemm_bt<1><<<dim3(32, 48), 256, 0, stream>>>(hs_bf, wqkv_bf, qkv_bf, vt_bf, 4096, 6144, 2048);

  attn<<<dim3(16, NHEADS, BATCH), 512, 0, stream>>>(qkv_bf, vt_bf, ctx_bf);

  gemm_bt<0><<<dim3(32, 16), 256, 0, stream>>>(ctx_bf, wout_bf, out, nullptr, 4096, 2048, 2048);
}

// Round 4
// 365.092 us; speedup vs baseline: 1.1761x; 1.0779x over previous
//
#include <hip/hip_runtime.h>
#include <stdint.h>

#define SEQ 2048
#define BATCH 2
#define HID 2048
#define NHEADS 16
#define HDIM 128
#define QKV_LD 6144
#define SCALE_F 0.08838834764831845f
#define LOG2E_F 1.4426950408889634f

typedef unsigned short u16;
using bf16x8 = __attribute__((ext_vector_type(8))) short;
using f32x4  = __attribute__((ext_vector_type(4))) float;

__device__ inline u16 f2bf(float f) {
  union { float f; uint32_t u; } c; c.f = f;
  uint32_t u = c.u;
  uint32_t r = (u + 0x7fffu + ((u >> 16) & 1u)) >> 16;
  return (u16)r;
}

__device__ inline void gl_lds16(const u16* g, u16* l) {
  __builtin_amdgcn_global_load_lds((const __attribute__((address_space(1))) void*)g,
                                   (__attribute__((address_space(3))) void*)l,
                                   16, 0, 0);
}

// One kernel converts all three inputs. Outputs contiguous in ws:
// [hs_bf | wqkv_bf (Q rows pre-scaled) | wout_bf].
__global__ void cvt_all(const float* __restrict__ hs, const float* __restrict__ wqkv,
                        const float* __restrict__ wout, u16* __restrict__ ws_out) {
  int i = blockIdx.x * blockDim.x + threadIdx.x;
  const float* src;
  int j;
  float sc = 1.0f;
  if (i < 2097152) { src = hs; j = i; }
  else if (i < 5242880) {
    j = i - 2097152; src = wqkv;
    const int f = j >> 9;
    if ((f % 384) < 128) sc = SCALE_F;             // Q rows carry the softmax scale
  } else { j = i - 5242880; src = wout; }
  float4 v = ((const float4*)src)[j];
  ushort4 o;
  o.x = f2bf(v.x * sc); o.y = f2bf(v.y * sc); o.z = f2bf(v.z * sc); o.w = f2bf(v.w * sc);
  ((ushort4*)ws_out)[i] = o;
}

// C[M,N] = A[M,K] @ B[N,K]^T, bf16 in, fp32 acc. 128x128 tile, BK=64, gl_lds x16
// staging with XOR chunk swizzle (0 bank conflicts, R5-measured).
// MODE 1 (QKV): bf16 out; V-blocks (bn%3==2, head=bn/3) written TRANSPOSED to vt
//   as packed 4B stores (two seq-positions per store), qkv V-part not written.
// MODE 0: f32 out, no vt.
template<int MODE>
__global__ __launch_bounds__(256)
void gemm_bt(const u16* __restrict__ A, const u16* __restrict__ Bw,
             void* __restrict__ Cout, u16* __restrict__ vt, int M, int N, int K) {
  __shared__ __align__(16) u16 As[128 * 64];
  __shared__ __align__(16) u16 Bs[128 * 64];
  const int bm = blockIdx.x, bn = blockIdx.y;
  const int tid = threadIdx.x;
  const int wave = tid >> 6, lane = tid & 63;
  const int quad = lane >> 4, l16 = lane & 15;
  const int wm = (wave >> 1) * 64, wn = (wave & 1) * 64;
  f32x4 acc[4][4] = {};

  const u16* Ablk = A + (size_t)(bm * 128) * K;
  const u16* Bblk = Bw + (size_t)(bn * 128) * K;

  for (int k0 = 0; k0 < K; k0 += 64) {
    __syncthreads();
    #pragma unroll
    for (int p = 0; p < 4; ++p) {
      int j = p * 256 + tid;
      int r = j >> 3, cs = j & 7, c = cs ^ (r & 7);
      gl_lds16(Ablk + (size_t)r * K + k0 + c * 8, As + (p * 256 + wave * 64) * 8);
      gl_lds16(Bblk + (size_t)r * K + k0 + c * 8, Bs + (p * 256 + wave * 64) * 8);
    }
    __syncthreads();
    #pragma unroll
    for (int ks = 0; ks < 2; ++ks) {
      bf16x8 af[4], bfr[4];
      #pragma unroll
      for (int mt = 0; mt < 4; ++mt) {
        int row = wm + mt * 16 + l16;
        int cc = (ks * 4 + quad) ^ (row & 7);
        af[mt] = *(const bf16x8*)&As[(row * 8 + cc) * 8];
      }
      #pragma unroll
      for (int nt = 0; nt < 4; ++nt) {
        int row = wn + nt * 16 + l16;
        int cc = (ks * 4 + quad) ^ (row & 7);
        bfr[nt] = *(const bf16x8*)&Bs[(row * 8 + cc) * 8];
      }
      #pragma unroll
      for (int mt = 0; mt < 4; ++mt)
        #pragma unroll
        for (int nt = 0; nt < 4; ++nt)
          acc[mt][nt] = __builtin_amdgcn_mfma_f32_16x16x32_bf16(af[mt], bfr[nt], acc[mt][nt], 0, 0, 0);
    }
  }

  if (MODE == 1 && (bn % 3) == 2) {
    // V block: C rows are tokens (row = s*2+b), cols are head-dims hd of head bn/3.
    // r=0:(s0,b0) r=1:(s0,b1) r=2:(s0+1,b0) r=3:(s0+1,b1); pack (r0,r2)/(r1,r3) -> 4B.
    const int h = bn / 3;
    u16* vt0 = vt + ((size_t)h * HDIM) * SEQ;                     // b=0
    u16* vt1 = vt + ((size_t)(NHEADS + h) * HDIM) * SEQ;          // b=1
    #pragma unroll
    for (int mt = 0; mt < 4; ++mt)
      #pragma unroll
      for (int nt = 0; nt < 4; ++nt) {
        const int hd = wn + nt * 16 + l16;
        const int s0 = (bm * 128 + wm + mt * 16 + quad * 4) >> 1;
        uint32_t w0 = (uint32_t)f2bf(acc[mt][nt][0]) | ((uint32_t)f2bf(acc[mt][nt][2]) << 16);
        uint32_t w1 = (uint32_t)f2bf(acc[mt][nt][1]) | ((uint32_t)f2bf(acc[mt][nt][3]) << 16);
        *(uint32_t*)&vt0[(size_t)hd * SEQ + s0] = w0;
        *(uint32_t*)&vt1[(size_t)hd * SEQ + s0] = w1;
      }
    return;
  }

  #pragma unroll
  for (int mt = 0; mt < 4; ++mt)
    #pragma unroll
    for (int nt = 0; nt < 4; ++nt)
      #pragma unroll
      for (int r = 0; r < 4; ++r) {
        int row = bm * 128 + wm + mt * 16 + quad * 4 + r;
        int col = bn * 128 + wn + nt * 16 + l16;
        float v = acc[mt][nt][r];
        if (MODE == 1) ((u16*)Cout)[(size_t)row * N + col] = f2bf(v);
        else           ((float*)Cout)[(size_t)row * N + col] = v;
      }
}

// Flash attention, no-max softmax (Q pre-scaled; scores bounded so exp can't overflow).
// R4: T3-minimum 2-phase pipeline. K/V double-buffered in LDS (100 KB total).
// Per K-tile: issue stage(t+1 -> buf^1) FIRST, compute on buf[cur], then ONE
// __syncthreads (its vmcnt(0) drain lands after ~650 cyc of MFMA+exp instead of
// before them). WAR-safe: buf^1's readers drained lgkmcnt before the previous
// barrier, stage(t+1) issued after it. setprio(1) around MFMA clusters (m191).
__global__ __launch_bounds__(512, 2)
void attn(const u16* __restrict__ qkv, const u16* __restrict__ vt_g, u16* __restrict__ ctx) {
  const int qt = blockIdx.x, head = blockIdx.y, b = blockIdx.z;
  const int q0 = qt * 256;
  __shared__ __align__(16) u16 Ks[2][64 * 128];   // 2 x 16 KB: 64 key-rows x 16 chunks
  __shared__ __align__(16) u16 Vt[2][144 * 64];   // 2 x 18 KB: 128 hd-rows + 16 ones/zero rows
  __shared__ __align__(16) u16 PsT[256 * 64];     // 32 KB: [q][key], swizzled chunks
  const int tid = threadIdx.x;
  const int wave = tid >> 6, lane = tid & 63;
  const int quad = lane >> 4, l16 = lane & 15;

  const u16* qkv_bh = qkv + (size_t)b * QKV_LD + head * 384;
  const u16* vt = vt_g + (size_t)(b * NHEADS + head) * HDIM * SEQ;

  // ones/zero rows 128..143 of both Vt buffers (row 128 = 1.0 bf16, rest 0).
  if (tid < 128) {
    const int row = 128 + (tid >> 3), c = tid & 7;
    const u16 v = (row == 128) ? (u16)0x3F80 : (u16)0;
    ushort4 q4; q4.x = v; q4.y = v; q4.z = v; q4.w = v;
    #pragma unroll
    for (int bb = 0; bb < 2; ++bb) {
      *(ushort4*)&Vt[bb][(row * 8 + c) * 8] = q4;
      *(ushort4*)&Vt[bb][(row * 8 + c) * 8 + 4] = q4;
    }
  }

  // ---- stage Q through Ks[0] buffer (4 rounds of 64 rows), frags into registers ----
  bf16x8 qf[2][4];   // [q-tile nt][ks]; used as B-operand later (same reg layout as A)
  #pragma unroll
  for (int h = 0; h < 4; ++h) {
    __syncthreads();
    #pragma unroll
    for (int p = 0; p < 2; ++p) {
      int j = p * 512 + tid;
      int r = j >> 4, cs = j & 15, c = cs ^ (r & 7);
      gl_lds16(qkv_bh + (size_t)(q0 + h * 64 + r) * (BATCH * QKV_LD) + c * 8,
               Ks[0] + (p * 512 + wave * 64) * 8);
    }
    __syncthreads();
    if ((wave >> 1) == h) {
      #pragma unroll
      for (int nt = 0; nt < 2; ++nt)
        #pragma unroll
        for (int ks = 0; ks < 4; ++ks) {
          int row = (wave & 1) * 32 + nt * 16 + l16;
          int cc = (ks * 4 + quad) ^ (row & 7);
          qf[nt][ks] = *(const bf16x8*)&Ks[0][(row * 16 + cc) * 8];
        }
    }
  }

  // stage K+Vt tile for a kt index into buffer bb (4 gl_lds/thread).
  auto stageKV = [&](int kt, int bb) {
    #pragma unroll
    for (int p = 0; p < 2; ++p) {
      int j = p * 512 + tid;
      int r = j >> 4, cs = j & 15, c = cs ^ (r & 7);
      gl_lds16(qkv_bh + (size_t)(kt + r) * (BATCH * QKV_LD) + 128 + c * 8,
               Ks[bb] + (p * 512 + wave * 64) * 8);
    }
    #pragma unroll
    for (int p = 0; p < 2; ++p) {
      int j = p * 512 + tid;
      int hd = j >> 3, cs = j & 7, c = cs ^ (hd & 7);
      gl_lds16(vt + (size_t)hd * SEQ + kt + c * 8,
               Vt[bb] + (p * 512 + wave * 64) * 8);
    }
  };

  f32x4 ot[9][2] = {};   // [hd-tile mt (8=ones/l)][q-tile nt]

  __syncthreads();               // Q readers done with Ks[0] before overwrite
  stageKV(0, 0);
  __syncthreads();               // tile 0 landed

  for (int it = 0; it < SEQ / 64; ++it) {
    const int cur = it & 1;
    if (it + 1 < SEQ / 64) stageKV((it + 1) * 64, cur ^ 1);   // issue-early (T14/T3)
    const u16* Kb = Ks[cur];
    const u16* Vb = Vt[cur];

    // S^T = K Q^T  (wave: 64 keys x 32 q-rows); element (key=mt*16+quad*4+r, q=nt*16+l16)
    f32x4 st[4][2] = {};
    #pragma unroll
    for (int ks = 0; ks < 4; ++ks) {
      bf16x8 kf[4];
      #pragma unroll
      for (int mt = 0; mt < 4; ++mt) {
        int key = mt * 16 + l16;
        int cc = (ks * 4 + quad) ^ (key & 7);
        kf[mt] = *(const bf16x8*)&Kb[(key * 16 + cc) * 8];
      }
      __builtin_amdgcn_s_setprio(1);
      #pragma unroll
      for (int mt = 0; mt < 4; ++mt)
        #pragma unroll
        for (int nt = 0; nt < 2; ++nt)
          st[mt][nt] = __builtin_amdgcn_mfma_f32_16x16x32_bf16(kf[mt], qf[nt][ks], st[mt][nt], 0, 0, 0);
      __builtin_amdgcn_s_setprio(0);
    }

    // p = exp2(s*log2e) -> bf16; 4 consecutive keys per lane -> one b64 write each
    #pragma unroll
    for (int mt = 0; mt < 4; ++mt)
      #pragma unroll
      for (int nt = 0; nt < 2; ++nt) {
        ushort4 pk;
        union { float f; uint32_t u; } cv;
        cv.f = __builtin_amdgcn_exp2f(st[mt][nt][0] * LOG2E_F); pk.x = (u16)(cv.u >> 16);
        cv.f = __builtin_amdgcn_exp2f(st[mt][nt][1] * LOG2E_F); pk.y = (u16)(cv.u >> 16);
        cv.f = __builtin_amdgcn_exp2f(st[mt][nt][2] * LOG2E_F); pk.z = (u16)(cv.u >> 16);
        cv.f = __builtin_amdgcn_exp2f(st[mt][nt][3] * LOG2E_F); pk.w = (u16)(cv.u >> 16);
        const int q = wave * 32 + nt * 16 + l16;
        const int kc = mt * 2 + (quad >> 1);
        *(ushort4*)&PsT[q * 64 + ((kc ^ (l16 & 7)) * 8 + (quad & 1) * 4)] = pk;
      }

    // O^T += V P  (A=Vt rows incl. ones, B=P^T; PsT rows are wave-private)
    #pragma unroll
    for (int ks = 0; ks < 2; ++ks) {
      bf16x8 pf[2], vf[9];
      #pragma unroll
      for (int nt = 0; nt < 2; ++nt) {
        const int q = wave * 32 + nt * 16 + l16;
        const int cc = (ks * 4 + quad) ^ (l16 & 7);
        pf[nt] = *(const bf16x8*)&PsT[q * 64 + cc * 8];
      }
      #pragma unroll
      for (int mt = 0; mt < 9; ++mt) {
        const int hd = mt * 16 + l16;
        const int cc = (ks * 4 + quad) ^ (hd & 7);
        vf[mt] = *(const bf16x8*)&Vb[(hd * 8 + cc) * 8];
      }
      __builtin_amdgcn_s_setprio(1);
      #pragma unroll
      for (int mt = 0; mt < 9; ++mt)
        #pragma unroll
        for (int nt = 0; nt < 2; ++nt)
          ot[mt][nt] = __builtin_amdgcn_mfma_f32_16x16x32_bf16(vf[mt], pf[nt], ot[mt][nt], 0, 0, 0);
      __builtin_amdgcn_s_setprio(0);
    }

    __syncthreads();   // drains stage(it+1) (after compute) + aligns waves
  }

  // epilogue: l[q] lives in ot[8][nt][0] at quad-0 lanes (m=0 row of ones-tile)
  #pragma unroll
  for (int nt = 0; nt < 2; ++nt) {
    const float lv = __shfl(ot[8][nt][0], l16);
    const float inv_l = 1.0f / lv;
    const int s = q0 + wave * 32 + nt * 16 + l16;
    u16* dst = ctx + ((size_t)s * BATCH + b) * HID + head * HDIM;
    #pragma unroll
    for (int mt = 0; mt < 8; ++mt) {
      ushort4 w;
      w.x = f2bf(ot[mt][nt][0] * inv_l);
      w.y = f2bf(ot[mt][nt][1] * inv_l);
      w.z = f2bf(ot[mt][nt][2] * inv_l);
      w.w = f2bf(ot[mt][nt][3] * inv_l);
      *(ushort4*)&dst[mt * 16 + quad * 4] = w;
    }
  }
}

extern "C" void kernel_launch(void* const* d_in, const int* in_sizes, int n_in,
                              void* d_out, int out_size, void* d_ws, size_t ws_size,
                              hipStream_t stream) {
  const float* hs   = (const float*)d_in[0];
  const float* wqkv = (const float*)d_in[1];
  const float* wout = (const float*)d_in[2];
  float* out = (float*)d_out;
  char* ws = (char*)d_ws;

  u16* hs_bf   = (u16*)(ws);               // 16 MB; dead after QKV GEMM
  u16* wqkv_bf = (u16*)(ws + 16777216);    // 24 MB
  u16* wout_bf = (u16*)(ws + 41943040);    //  8 MB
  u16* qkv_bf  = (u16*)(ws + 50331648);    // 48 MB (V-part unused/unwritten)
  u16* vt_bf   = (u16*)(ws + 100663296);   // 16 MB, written by QKV GEMM epilogue
  u16* ctx_bf  = hs_bf;                    // reuse: attn runs after QKV GEMM

  cvt_all<<<24576, 256, 0, stream>>>(hs, wqkv, wout, (u16*)ws);

  gemm_bt<1><<<dim3(32, 48), 256, 0, stream>>>(hs_bf, wqkv_bf, qkv_bf, vt_bf, 4096, 6144, 2048);

  attn<<<dim3(8, NHEADS, BATCH), 512, 0, stream>>>(qkv_bf, vt_bf, ctx_bf);

  gemm_bt<0><<<dim3(32, 16), 256, 0, stream>>>(ctx_bf, wout_bf, out, nullptr, 4096, 2048, 2048);
}